// Round 1
// baseline (834.276 us; speedup 1.0000x reference)
//
#include <hip/hip_runtime.h>
#include <math.h>

typedef __bf16 bf16_t;
typedef __bf16 bf16x8 __attribute__((ext_vector_type(8)));
typedef __bf16 bf16x4 __attribute__((ext_vector_type(4)));
typedef float f32x4 __attribute__((ext_vector_type(4)));

#define TOKS 2048
#define INF 2048
#define JNF 8192
#define ONF 2048
#define LDA 40  // LDS row stride (bf16) for 32-wide K tile, padded: 2-way bank alias only

// ---------------- prep kernels ----------------

__global__ __launch_bounds__(256) void prep_mu_thr(
    const float* __restrict__ med, const float* __restrict__ aad,
    const float* __restrict__ gth, float debiaser,
    float* __restrict__ mu, float* __restrict__ thr) {
  int gid = blockIdx.x * 256 + threadIdx.x;  // 65536 threads
  if (gid < INF) mu[gid] = med[gid] * debiaser;
  int i = gid & (INF - 1);
  float stdv = aad[i] * debiaser / 2.5066282746310002f;  // sqrt(2*pi)
  thr[gid] = gth[gid] * stdv * 45.254833995939045f;      // sqrt(2048)
}

__global__ __launch_bounds__(256) void prep_x(
    const float* __restrict__ x, const float* __restrict__ mu,
    float* __restrict__ xd, bf16_t* __restrict__ xb) {
  int idx = (blockIdx.x * 256 + threadIdx.x) * 4;
  f32x4 xv = *(const f32x4*)&x[idx];
  f32x4 muv = *(const f32x4*)&mu[idx & (INF - 1)];
  f32x4 d = xv - muv;
  *(f32x4*)&xd[idx] = d;
  bf16x4 o;
  o[0] = (bf16_t)xv[0]; o[1] = (bf16_t)xv[1];
  o[2] = (bf16_t)xv[2]; o[3] = (bf16_t)xv[3];
  *(bf16x4*)&xb[idx] = o;
}

// src [INF, JNF] fp32 -> dst [JNF, INF] bf16
__global__ __launch_bounds__(256) void transpose_cast(
    const float* __restrict__ src, bf16_t* __restrict__ dst) {
  __shared__ float tile[32][33];
  int j0 = blockIdx.x * 32;
  int i0 = blockIdx.y * 32;
  int r = threadIdx.x >> 3;
  int c = (threadIdx.x & 7) * 4;
  f32x4 v = *(const f32x4*)&src[(i0 + r) * JNF + j0 + c];
  tile[r][c] = v[0]; tile[r][c + 1] = v[1]; tile[r][c + 2] = v[2]; tile[r][c + 3] = v[3];
  __syncthreads();
  bf16x4 o;
  o[0] = (bf16_t)tile[c + 0][r];
  o[1] = (bf16_t)tile[c + 1][r];
  o[2] = (bf16_t)tile[c + 2][r];
  o[3] = (bf16_t)tile[c + 3][r];
  *(bf16x4*)&dst[(j0 + r) * INF + i0 + c] = o;
}

__global__ __launch_bounds__(256) void cast_bf16(
    const float* __restrict__ src, bf16_t* __restrict__ dst) {
  int idx = (blockIdx.x * 256 + threadIdx.x) * 8;
  f32x4 a = *(const f32x4*)&src[idx];
  f32x4 b = *(const f32x4*)&src[idx + 4];
  bf16x8 o;
  o[0] = (bf16_t)a[0]; o[1] = (bf16_t)a[1]; o[2] = (bf16_t)a[2]; o[3] = (bf16_t)a[3];
  o[4] = (bf16_t)b[0]; o[5] = (bf16_t)b[1]; o[6] = (bf16_t)b[2]; o[7] = (bf16_t)b[3];
  *(bf16x8*)&dst[idx] = o;
}

__global__ __launch_bounds__(256) void c_init(
    const float* __restrict__ gb, float* __restrict__ c) {
  int j = blockIdx.x * 256 + threadIdx.x;
  c[j] = gb[j];
}

// c[j] += sum_i gw[i,j]*mu[i], split over 8 i-ranges
__global__ __launch_bounds__(256) void c_part(
    const float* __restrict__ gw, const float* __restrict__ mu,
    float* __restrict__ c) {
  int jb = blockIdx.x & 31;
  int ib = blockIdx.x >> 5;
  int j = jb * 256 + threadIdx.x;
  int i0 = ib * 256;
  float s = 0.f;
#pragma unroll 4
  for (int i = 0; i < 256; ++i) s += gw[(size_t)(i0 + i) * JNF + j] * mu[i0 + i];
  atomicAdd(&c[j], s);
}

__global__ __launch_bounds__(256) void count_active(
    const float* __restrict__ xd, const float* __restrict__ thr,
    float* __restrict__ dense, float* __restrict__ active) {
  int t = blockIdx.x;
  int tid = threadIdx.x;
  int cnt = 0;
  for (int r = 0; r < 8; ++r) {
    int i = (r << 8) + tid;
    float v = fabsf(xd[t * INF + i]);
#pragma unroll
    for (int n = 0; n < 32; ++n) cnt += (v > thr[(n << 11) + i]) ? 1 : 0;
  }
  for (int off = 32; off; off >>= 1) cnt += __shfl_down(cnt, off);
  __shared__ int red[4];
  int wv = tid >> 6;
  if ((tid & 63) == 0) red[wv] = cnt;
  __syncthreads();
  if (tid == 0) {
    int tot = red[0] + red[1] + red[2] + red[3];
    active[t] = 256.0f * (float)tot;
    dense[t] = 16777216.0f;
  }
}

// ---------------- GEMM kernels ----------------
// tile 128x128, BK=32, 4 waves (2x2), each wave 4x4 mfma_f32_16x16x32_bf16

__global__ __launch_bounds__(256) void gate_gemm(
    const float* __restrict__ xd, const float* __restrict__ thr,
    const bf16_t* __restrict__ gwT, const float* __restrict__ cj,
    float* __restrict__ g) {
  __shared__ bf16_t Al[128 * LDA];
  __shared__ bf16_t Bl[128 * LDA];
  int tid = threadIdx.x;
  int t0 = blockIdx.y * 128;
  int j0 = blockIdx.x * 128;
  int n = blockIdx.x >> 1;  // stripe
  int lane = tid & 63;
  int wv = tid >> 6;
  int wr = (wv & 1) * 64;
  int wc = (wv >> 1) * 64;
  int m16 = lane & 15, q = lane >> 4;
  f32x4 acc[4][4] = {};
  for (int k0 = 0; k0 < INF; k0 += 32) {
    // stage A (masked xd -> bf16): 128x32 fp32, 4 floats/thread/iter
#pragma unroll
    for (int it = 0; it < 4; ++it) {
      int ci = tid + it * 256;
      int row = ci >> 3, c4 = (ci & 7) * 4;
      f32x4 xv = *(const f32x4*)&xd[(size_t)(t0 + row) * INF + k0 + c4];
      f32x4 tv = *(const f32x4*)&thr[n * INF + k0 + c4];
      bf16x4 o;
      o[0] = (bf16_t)(fabsf(xv[0]) > tv[0] ? xv[0] : 0.f);
      o[1] = (bf16_t)(fabsf(xv[1]) > tv[1] ? xv[1] : 0.f);
      o[2] = (bf16_t)(fabsf(xv[2]) > tv[2] ? xv[2] : 0.f);
      o[3] = (bf16_t)(fabsf(xv[3]) > tv[3] ? xv[3] : 0.f);
      *(bf16x4*)&Al[row * LDA + c4] = o;
    }
    // stage B (gwT): 128x32 bf16, 8 bf16/thread/iter
#pragma unroll
    for (int it = 0; it < 2; ++it) {
      int ci = tid + it * 256;
      int row = ci >> 2, cc = (ci & 3) * 8;
      *(bf16x8*)&Bl[row * LDA + cc] = *(const bf16x8*)&gwT[(size_t)(j0 + row) * INF + k0 + cc];
    }
    __syncthreads();
    bf16x8 af[4], bf[4];
#pragma unroll
    for (int mi = 0; mi < 4; ++mi) af[mi] = *(bf16x8*)&Al[(wr + mi * 16 + m16) * LDA + q * 8];
#pragma unroll
    for (int ni = 0; ni < 4; ++ni) bf[ni] = *(bf16x8*)&Bl[(wc + ni * 16 + m16) * LDA + q * 8];
#pragma unroll
    for (int mi = 0; mi < 4; ++mi)
#pragma unroll
      for (int ni = 0; ni < 4; ++ni)
        acc[mi][ni] = __builtin_amdgcn_mfma_f32_16x16x32_bf16(af[mi], bf[ni], acc[mi][ni], 0, 0, 0);
    __syncthreads();
  }
#pragma unroll
  for (int mi = 0; mi < 4; ++mi)
#pragma unroll
    for (int ni = 0; ni < 4; ++ni) {
      int col = j0 + wc + ni * 16 + m16;
      float cadd = cj[col];
#pragma unroll
      for (int r = 0; r < 4; ++r) {
        int row = t0 + wr + mi * 16 + q * 4 + r;
        g[(size_t)row * JNF + col] = acc[mi][ni][r] + cadd;
      }
    }
}

__global__ __launch_bounds__(256) void up_gemm(
    const bf16_t* __restrict__ xb, const bf16_t* __restrict__ upT,
    const float* __restrict__ ub, const float* __restrict__ g,
    bf16_t* __restrict__ h) {
  __shared__ bf16_t Al[128 * LDA];
  __shared__ bf16_t Bl[128 * LDA];
  int tid = threadIdx.x;
  int t0 = blockIdx.y * 128;
  int j0 = blockIdx.x * 128;
  int lane = tid & 63;
  int wv = tid >> 6;
  int wr = (wv & 1) * 64;
  int wc = (wv >> 1) * 64;
  int m16 = lane & 15, q = lane >> 4;
  f32x4 acc[4][4] = {};
  for (int k0 = 0; k0 < INF; k0 += 32) {
#pragma unroll
    for (int it = 0; it < 2; ++it) {
      int ci = tid + it * 256;
      int row = ci >> 2, cc = (ci & 3) * 8;
      *(bf16x8*)&Al[row * LDA + cc] = *(const bf16x8*)&xb[(size_t)(t0 + row) * INF + k0 + cc];
      *(bf16x8*)&Bl[row * LDA + cc] = *(const bf16x8*)&upT[(size_t)(j0 + row) * INF + k0 + cc];
    }
    __syncthreads();
    bf16x8 af[4], bf[4];
#pragma unroll
    for (int mi = 0; mi < 4; ++mi) af[mi] = *(bf16x8*)&Al[(wr + mi * 16 + m16) * LDA + q * 8];
#pragma unroll
    for (int ni = 0; ni < 4; ++ni) bf[ni] = *(bf16x8*)&Bl[(wc + ni * 16 + m16) * LDA + q * 8];
#pragma unroll
    for (int mi = 0; mi < 4; ++mi)
#pragma unroll
      for (int ni = 0; ni < 4; ++ni)
        acc[mi][ni] = __builtin_amdgcn_mfma_f32_16x16x32_bf16(af[mi], bf[ni], acc[mi][ni], 0, 0, 0);
    __syncthreads();
  }
#pragma unroll
  for (int mi = 0; mi < 4; ++mi)
#pragma unroll
    for (int ni = 0; ni < 4; ++ni) {
      int col = j0 + wc + ni * 16 + m16;
      float bias = ub[col];
#pragma unroll
      for (int r = 0; r < 4; ++r) {
        int row = t0 + wr + mi * 16 + q * 4 + r;
        float upv = acc[mi][ni][r] + bias;
        float gv = g[(size_t)row * JNF + col];
        float hv = (gv / (1.f + expf(-gv))) * upv;
        h[(size_t)row * JNF + col] = (bf16_t)hv;
      }
    }
}

__global__ __launch_bounds__(256) void down_gemm(
    const bf16_t* __restrict__ h, const bf16_t* __restrict__ dwb,
    const float* __restrict__ db, float* __restrict__ y) {
  __shared__ bf16_t Al[128 * LDA];
  __shared__ bf16_t Bl[128 * LDA];
  int tid = threadIdx.x;
  int t0 = blockIdx.y * 128;
  int o0 = blockIdx.x * 128;
  int lane = tid & 63;
  int wv = tid >> 6;
  int wr = (wv & 1) * 64;
  int wc = (wv >> 1) * 64;
  int m16 = lane & 15, q = lane >> 4;
  f32x4 acc[4][4] = {};
  for (int k0 = 0; k0 < JNF; k0 += 32) {
#pragma unroll
    for (int it = 0; it < 2; ++it) {
      int ci = tid + it * 256;
      int row = ci >> 2, cc = (ci & 3) * 8;
      *(bf16x8*)&Al[row * LDA + cc] = *(const bf16x8*)&h[(size_t)(t0 + row) * JNF + k0 + cc];
      *(bf16x8*)&Bl[row * LDA + cc] = *(const bf16x8*)&dwb[(size_t)(o0 + row) * JNF + k0 + cc];
    }
    __syncthreads();
    bf16x8 af[4], bf[4];
#pragma unroll
    for (int mi = 0; mi < 4; ++mi) af[mi] = *(bf16x8*)&Al[(wr + mi * 16 + m16) * LDA + q * 8];
#pragma unroll
    for (int ni = 0; ni < 4; ++ni) bf[ni] = *(bf16x8*)&Bl[(wc + ni * 16 + m16) * LDA + q * 8];
#pragma unroll
    for (int mi = 0; mi < 4; ++mi)
#pragma unroll
      for (int ni = 0; ni < 4; ++ni)
        acc[mi][ni] = __builtin_amdgcn_mfma_f32_16x16x32_bf16(af[mi], bf[ni], acc[mi][ni], 0, 0, 0);
    __syncthreads();
  }
#pragma unroll
  for (int mi = 0; mi < 4; ++mi)
#pragma unroll
    for (int ni = 0; ni < 4; ++ni) {
      int col = o0 + wc + ni * 16 + m16;
      float bias = db[col];
#pragma unroll
      for (int r = 0; r < 4; ++r) {
        int row = t0 + wr + mi * 16 + q * 4 + r;
        y[(size_t)row * ONF + col] = acc[mi][ni][r] + bias;
      }
    }
}

// ---------------- launcher ----------------

extern "C" void kernel_launch(void* const* d_in, const int* in_sizes, int n_in,
                              void* d_out, int out_size, void* d_ws, size_t ws_size,
                              hipStream_t stream) {
  (void)in_sizes; (void)n_in; (void)out_size; (void)ws_size;
  const float* x   = (const float*)d_in[0];
  const float* gw  = (const float*)d_in[1];
  const float* gb  = (const float*)d_in[2];
  const float* gth = (const float*)d_in[3];
  const float* med = (const float*)d_in[4];
  const float* aad = (const float*)d_in[5];
  const float* uw  = (const float*)d_in[6];
  const float* ub  = (const float*)d_in[7];
  const float* dw  = (const float*)d_in[8];
  const float* db  = (const float*)d_in[9];

  float* out = (float*)d_out;
  float* y = out;                       // [2048,2048]
  float* dense = out + 4194304;         // [2048]
  float* active = dense + 2048;         // [2048]

  char* ws = (char*)d_ws;
  float* mu    = (float*)(ws + 0);          //   8 KB
  float* thr   = (float*)(ws + 8192);       // 256 KB
  float* cj    = (float*)(ws + 270336);     //  32 KB
  float* xd    = (float*)(ws + 303104);     //  16 MB
  bf16_t* xb   = (bf16_t*)(ws + 17080320);  //   8 MB
  bf16_t* gwT  = (bf16_t*)(ws + 25468928);  //  32 MB
  bf16_t* upT  = (bf16_t*)(ws + 59023360);  //  32 MB
  bf16_t* dwb  = (bf16_t*)(ws + 92577792);  //  32 MB
  float* g     = (float*)(ws + 126132224);  //  64 MB
  bf16_t* hb   = (bf16_t*)(ws + 193241088); //  32 MB  -> total ~216 MB

  float debiaser = (float)(1.0 / (1e-7 + (1.0 - pow(0.99, 1000.0))));

  prep_mu_thr<<<256, 256, 0, stream>>>(med, aad, gth, debiaser, mu, thr);
  prep_x<<<4096, 256, 0, stream>>>(x, mu, xd, xb);
  transpose_cast<<<dim3(256, 64), 256, 0, stream>>>(gw, gwT);
  transpose_cast<<<dim3(256, 64), 256, 0, stream>>>(uw, upT);
  cast_bf16<<<8192, 256, 0, stream>>>(dw, dwb);
  c_init<<<32, 256, 0, stream>>>(gb, cj);
  c_part<<<256, 256, 0, stream>>>(gw, mu, cj);
  count_active<<<2048, 256, 0, stream>>>(xd, thr, dense, active);
  gate_gemm<<<dim3(64, 16), 256, 0, stream>>>(xd, thr, gwT, cj, g);
  up_gemm<<<dim3(64, 16), 256, 0, stream>>>(xb, upT, ub, g, hb);
  down_gemm<<<dim3(16, 16), 256, 0, stream>>>(hb, dwb, db, y);
}

// Round 2
// 770.941 us; speedup vs baseline: 1.0822x; 1.0822x over previous
//
#include <hip/hip_runtime.h>
#include <math.h>
#include <stdint.h>

typedef __bf16 bf16_t;
typedef __bf16 bf16x8 __attribute__((ext_vector_type(8)));
typedef __bf16 bf16x4 __attribute__((ext_vector_type(4)));
typedef float f32x4 __attribute__((ext_vector_type(4)));

#define TOKS 2048
#define INF 2048
#define JNF 8192
#define ONF 2048

// ---------------- async staging helpers ----------------
// Tile: 128 rows x 32 k bf16, unpadded (row stride 32 elems = 64 B), 8 KB.
// 512 chunks of 16 B. Chunk c: row = c>>2, slot = c&3. Slot s of row holds
// SOURCE k-quad (s ^ ((row>>1)&3)) -> fragment reads are <=2-way bank aliased
// (free, m136); global_load_lds writes are lane-contiguous (conflict-free).

__device__ __forceinline__ void stage_async(const bf16_t* __restrict__ src, size_t ld,
                                            bf16_t* lds, int tid) {
#pragma unroll
  for (int r = 0; r < 2; ++r) {
    int c = r * 256 + tid;
    int row = c >> 2;
    int kq = (c & 3) ^ ((row >> 1) & 3);
    const bf16_t* g = src + (size_t)row * ld + kq * 8;
    bf16_t* l = lds + (size_t)(r * 256 + (tid & 0xC0)) * 8;  // wave-uniform base
    __builtin_amdgcn_global_load_lds((const __attribute__((address_space(1))) void*)g,
                                     (__attribute__((address_space(3))) void*)l,
                                     16, 0, 0);
  }
}

__device__ __forceinline__ bf16x8 frag_ld(const bf16_t* lds, int row, int q) {
  int kq = q ^ ((row >> 1) & 3);
  return *(const bf16x8*)&lds[row * 32 + kq * 8];
}

// ---------------- prep kernels ----------------

__global__ __launch_bounds__(256) void prep_mu_thr(
    const float* __restrict__ med, const float* __restrict__ aad,
    const float* __restrict__ gth, float debiaser,
    float* __restrict__ mu, float* __restrict__ thr) {
  int gid = blockIdx.x * 256 + threadIdx.x;  // 65536 threads
  if (gid < INF) mu[gid] = med[gid] * debiaser;
  int i = gid & (INF - 1);
  float stdv = aad[i] * debiaser / 2.5066282746310002f;  // sqrt(2*pi)
  thr[gid] = gth[gid] * stdv * 45.254833995939045f;      // sqrt(2048)
}

__global__ __launch_bounds__(256) void prep_x(
    const float* __restrict__ x, const float* __restrict__ mu,
    float* __restrict__ xd, bf16_t* __restrict__ xb) {
  int idx = (blockIdx.x * 256 + threadIdx.x) * 4;
  f32x4 xv = *(const f32x4*)&x[idx];
  f32x4 muv = *(const f32x4*)&mu[idx & (INF - 1)];
  f32x4 d = xv - muv;
  *(f32x4*)&xd[idx] = d;
  bf16x4 o;
  o[0] = (bf16_t)xv[0]; o[1] = (bf16_t)xv[1];
  o[2] = (bf16_t)xv[2]; o[3] = (bf16_t)xv[3];
  *(bf16x4*)&xb[idx] = o;
}

// src [INF, JNF] fp32 -> dst [JNF, INF] bf16
__global__ __launch_bounds__(256) void transpose_cast(
    const float* __restrict__ src, bf16_t* __restrict__ dst) {
  __shared__ float tile[32][33];
  int j0 = blockIdx.x * 32;
  int i0 = blockIdx.y * 32;
  int r = threadIdx.x >> 3;
  int c = (threadIdx.x & 7) * 4;
  f32x4 v = *(const f32x4*)&src[(i0 + r) * JNF + j0 + c];
  tile[r][c] = v[0]; tile[r][c + 1] = v[1]; tile[r][c + 2] = v[2]; tile[r][c + 3] = v[3];
  __syncthreads();
  bf16x4 o;
  o[0] = (bf16_t)tile[c + 0][r];
  o[1] = (bf16_t)tile[c + 1][r];
  o[2] = (bf16_t)tile[c + 2][r];
  o[3] = (bf16_t)tile[c + 3][r];
  *(bf16x4*)&dst[(j0 + r) * INF + i0 + c] = o;
}

__global__ __launch_bounds__(256) void cast_bf16(
    const float* __restrict__ src, bf16_t* __restrict__ dst) {
  int idx = (blockIdx.x * 256 + threadIdx.x) * 8;
  f32x4 a = *(const f32x4*)&src[idx];
  f32x4 b = *(const f32x4*)&src[idx + 4];
  bf16x8 o;
  o[0] = (bf16_t)a[0]; o[1] = (bf16_t)a[1]; o[2] = (bf16_t)a[2]; o[3] = (bf16_t)a[3];
  o[4] = (bf16_t)b[0]; o[5] = (bf16_t)b[1]; o[6] = (bf16_t)b[2]; o[7] = (bf16_t)b[3];
  *(bf16x8*)&dst[idx] = o;
}

__global__ __launch_bounds__(256) void c_init(
    const float* __restrict__ gb, float* __restrict__ c) {
  int j = blockIdx.x * 256 + threadIdx.x;
  c[j] = gb[j];
}

// c[j] += sum_i gw[i,j]*mu[i], split over 8 i-ranges
__global__ __launch_bounds__(256) void c_part(
    const float* __restrict__ gw, const float* __restrict__ mu,
    float* __restrict__ c) {
  int jb = blockIdx.x & 31;
  int ib = blockIdx.x >> 5;
  int j = jb * 256 + threadIdx.x;
  int i0 = ib * 256;
  float s = 0.f;
#pragma unroll 4
  for (int i = 0; i < 256; ++i) s += gw[(size_t)(i0 + i) * JNF + j] * mu[i0 + i];
  atomicAdd(&c[j], s);
}

__global__ __launch_bounds__(256) void count_active(
    const float* __restrict__ xd, const float* __restrict__ thr,
    float* __restrict__ dense, float* __restrict__ active) {
  int t = blockIdx.x;
  int tid = threadIdx.x;
  int cnt = 0;
  for (int r = 0; r < 8; ++r) {
    int i = (r << 8) + tid;
    float v = fabsf(xd[t * INF + i]);
#pragma unroll
    for (int n = 0; n < 32; ++n) cnt += (v > thr[(n << 11) + i]) ? 1 : 0;
  }
  for (int off = 32; off; off >>= 1) cnt += __shfl_down(cnt, off);
  __shared__ int red[4];
  int wv = tid >> 6;
  if ((tid & 63) == 0) red[wv] = cnt;
  __syncthreads();
  if (tid == 0) {
    int tot = red[0] + red[1] + red[2] + red[3];
    active[t] = 256.0f * (float)tot;
    dense[t] = 16777216.0f;
  }
}

// ---------------- GEMM kernels ----------------
// tile 128x128, BK=32, 4 waves (2x2), each wave 4x4 mfma_f32_16x16x32_bf16

__global__ __launch_bounds__(256) void gate_gemm(
    const float* __restrict__ xd, const float* __restrict__ thr,
    const bf16_t* __restrict__ gwT, const float* __restrict__ cj,
    float* __restrict__ g) {
  __shared__ bf16_t Al[128 * 32];
  __shared__ bf16_t Bl[128 * 32];
  int tid = threadIdx.x;
  int t0 = blockIdx.y * 128;
  int j0 = blockIdx.x * 128;
  int n = blockIdx.x >> 1;  // stripe
  int lane = tid & 63;
  int wv = tid >> 6;
  int wr = (wv & 1) * 64;
  int wc = (wv >> 1) * 64;
  int m16 = lane & 15, q = lane >> 4;
  f32x4 acc[4][4] = {};
  for (int k0 = 0; k0 < INF; k0 += 32) {
    // async-stage B first so it's in flight during A's VALU work
    stage_async(gwT + (size_t)j0 * INF + k0, INF, Bl, tid);
    // stage A (masked xd -> bf16): swizzled layout, lane-contiguous ds_write
#pragma unroll
    for (int r = 0; r < 2; ++r) {
      int c = r * 256 + tid;
      int row = c >> 2;
      int kq = (c & 3) ^ ((row >> 1) & 3);
      const float* xp = &xd[(size_t)(t0 + row) * INF + k0 + kq * 8];
      const float* tp = &thr[n * INF + k0 + kq * 8];
      f32x4 x0 = *(const f32x4*)xp;
      f32x4 x1 = *(const f32x4*)(xp + 4);
      f32x4 h0 = *(const f32x4*)tp;
      f32x4 h1 = *(const f32x4*)(tp + 4);
      bf16x8 o;
      o[0] = (bf16_t)(fabsf(x0[0]) > h0[0] ? x0[0] : 0.f);
      o[1] = (bf16_t)(fabsf(x0[1]) > h0[1] ? x0[1] : 0.f);
      o[2] = (bf16_t)(fabsf(x0[2]) > h0[2] ? x0[2] : 0.f);
      o[3] = (bf16_t)(fabsf(x0[3]) > h0[3] ? x0[3] : 0.f);
      o[4] = (bf16_t)(fabsf(x1[0]) > h1[0] ? x1[0] : 0.f);
      o[5] = (bf16_t)(fabsf(x1[1]) > h1[1] ? x1[1] : 0.f);
      o[6] = (bf16_t)(fabsf(x1[2]) > h1[2] ? x1[2] : 0.f);
      o[7] = (bf16_t)(fabsf(x1[3]) > h1[3] ? x1[3] : 0.f);
      *(bf16x8*)&Al[row * 32 + (c & 3) * 8] = o;
    }
    __syncthreads();
    bf16x8 af[4], bf[4];
#pragma unroll
    for (int mi = 0; mi < 4; ++mi) af[mi] = frag_ld(Al, wr + mi * 16 + m16, q);
#pragma unroll
    for (int ni = 0; ni < 4; ++ni) bf[ni] = frag_ld(Bl, wc + ni * 16 + m16, q);
#pragma unroll
    for (int mi = 0; mi < 4; ++mi)
#pragma unroll
      for (int ni = 0; ni < 4; ++ni)
        acc[mi][ni] = __builtin_amdgcn_mfma_f32_16x16x32_bf16(af[mi], bf[ni], acc[mi][ni], 0, 0, 0);
    __syncthreads();
  }
#pragma unroll
  for (int mi = 0; mi < 4; ++mi)
#pragma unroll
    for (int ni = 0; ni < 4; ++ni) {
      int col = j0 + wc + ni * 16 + m16;
      float cadd = cj[col];
#pragma unroll
      for (int r = 0; r < 4; ++r) {
        int row = t0 + wr + mi * 16 + q * 4 + r;
        g[(size_t)row * JNF + col] = acc[mi][ni][r] + cadd;
      }
    }
}

__global__ __launch_bounds__(256) void up_gemm(
    const bf16_t* __restrict__ xb, const bf16_t* __restrict__ upT,
    const float* __restrict__ ub, const float* __restrict__ g,
    bf16_t* __restrict__ h) {
  __shared__ bf16_t Al[128 * 32];
  __shared__ bf16_t Bl[128 * 32];
  int tid = threadIdx.x;
  int t0 = blockIdx.y * 128;
  int j0 = blockIdx.x * 128;
  int lane = tid & 63;
  int wv = tid >> 6;
  int wr = (wv & 1) * 64;
  int wc = (wv >> 1) * 64;
  int m16 = lane & 15, q = lane >> 4;
  f32x4 acc[4][4] = {};
  for (int k0 = 0; k0 < INF; k0 += 32) {
    stage_async(xb + (size_t)t0 * INF + k0, INF, Al, tid);
    stage_async(upT + (size_t)j0 * INF + k0, INF, Bl, tid);
    __syncthreads();
    bf16x8 af[4], bf[4];
#pragma unroll
    for (int mi = 0; mi < 4; ++mi) af[mi] = frag_ld(Al, wr + mi * 16 + m16, q);
#pragma unroll
    for (int ni = 0; ni < 4; ++ni) bf[ni] = frag_ld(Bl, wc + ni * 16 + m16, q);
#pragma unroll
    for (int mi = 0; mi < 4; ++mi)
#pragma unroll
      for (int ni = 0; ni < 4; ++ni)
        acc[mi][ni] = __builtin_amdgcn_mfma_f32_16x16x32_bf16(af[mi], bf[ni], acc[mi][ni], 0, 0, 0);
    __syncthreads();
  }
#pragma unroll
  for (int mi = 0; mi < 4; ++mi)
#pragma unroll
    for (int ni = 0; ni < 4; ++ni) {
      int col = j0 + wc + ni * 16 + m16;
      float bias = ub[col];
#pragma unroll
      for (int r = 0; r < 4; ++r) {
        int row = t0 + wr + mi * 16 + q * 4 + r;
        float upv = acc[mi][ni][r] + bias;
        float gv = g[(size_t)row * JNF + col];
        float hv = (gv / (1.f + expf(-gv))) * upv;
        h[(size_t)row * JNF + col] = (bf16_t)hv;
      }
    }
}

// split-K partial: z-th K-chunk of 2048, no bias
__global__ __launch_bounds__(256) void down_gemm(
    const bf16_t* __restrict__ h, const bf16_t* __restrict__ dwb,
    float* __restrict__ part) {
  __shared__ bf16_t Al[128 * 32];
  __shared__ bf16_t Bl[128 * 32];
  int tid = threadIdx.x;
  int t0 = blockIdx.y * 128;
  int o0 = blockIdx.x * 128;
  int kz = blockIdx.z * 2048;
  int lane = tid & 63;
  int wv = tid >> 6;
  int wr = (wv & 1) * 64;
  int wc = (wv >> 1) * 64;
  int m16 = lane & 15, q = lane >> 4;
  f32x4 acc[4][4] = {};
  for (int k0 = kz; k0 < kz + 2048; k0 += 32) {
    stage_async(h + (size_t)t0 * JNF + k0, JNF, Al, tid);
    stage_async(dwb + (size_t)o0 * JNF + k0, JNF, Bl, tid);
    __syncthreads();
    bf16x8 af[4], bf[4];
#pragma unroll
    for (int mi = 0; mi < 4; ++mi) af[mi] = frag_ld(Al, wr + mi * 16 + m16, q);
#pragma unroll
    for (int ni = 0; ni < 4; ++ni) bf[ni] = frag_ld(Bl, wc + ni * 16 + m16, q);
#pragma unroll
    for (int mi = 0; mi < 4; ++mi)
#pragma unroll
      for (int ni = 0; ni < 4; ++ni)
        acc[mi][ni] = __builtin_amdgcn_mfma_f32_16x16x32_bf16(af[mi], bf[ni], acc[mi][ni], 0, 0, 0);
    __syncthreads();
  }
  float* dst = part + (size_t)blockIdx.z * (TOKS * ONF);
#pragma unroll
  for (int mi = 0; mi < 4; ++mi)
#pragma unroll
    for (int ni = 0; ni < 4; ++ni) {
      int col = o0 + wc + ni * 16 + m16;
#pragma unroll
      for (int r = 0; r < 4; ++r) {
        int row = t0 + wr + mi * 16 + q * 4 + r;
        dst[(size_t)row * ONF + col] = acc[mi][ni][r];
      }
    }
}

__global__ __launch_bounds__(256) void down_reduce(
    const float* __restrict__ part, const float* __restrict__ db,
    float* __restrict__ y) {
  int idx = (blockIdx.x * 256 + threadIdx.x) * 4;
  f32x4 a = *(const f32x4*)&part[idx];
  f32x4 b = *(const f32x4*)&part[idx + 4194304];
  f32x4 c = *(const f32x4*)&part[idx + 2 * 4194304];
  f32x4 d = *(const f32x4*)&part[idx + 3 * 4194304];
  f32x4 bias = *(const f32x4*)&db[idx & (ONF - 1)];
  *(f32x4*)&y[idx] = a + b + c + d + bias;
}

// ---------------- launcher ----------------

extern "C" void kernel_launch(void* const* d_in, const int* in_sizes, int n_in,
                              void* d_out, int out_size, void* d_ws, size_t ws_size,
                              hipStream_t stream) {
  (void)in_sizes; (void)n_in; (void)out_size; (void)ws_size;
  const float* x   = (const float*)d_in[0];
  const float* gw  = (const float*)d_in[1];
  const float* gb  = (const float*)d_in[2];
  const float* gth = (const float*)d_in[3];
  const float* med = (const float*)d_in[4];
  const float* aad = (const float*)d_in[5];
  const float* uw  = (const float*)d_in[6];
  const float* ub  = (const float*)d_in[7];
  const float* dw  = (const float*)d_in[8];
  const float* db  = (const float*)d_in[9];

  float* out = (float*)d_out;
  float* y = out;                       // [2048,2048]
  float* dense = out + 4194304;         // [2048]
  float* active = dense + 2048;         // [2048]

  char* ws = (char*)d_ws;
  float* mu    = (float*)(ws + 0);          //   8 KB
  float* thr   = (float*)(ws + 8192);       // 256 KB
  float* cj    = (float*)(ws + 270336);     //  32 KB
  float* xd    = (float*)(ws + 303104);     //  16 MB
  bf16_t* xb   = (bf16_t*)(ws + 17080320);  //   8 MB
  bf16_t* gwT  = (bf16_t*)(ws + 25468928);  //  32 MB
  bf16_t* upT  = (bf16_t*)(ws + 59023360);  //  32 MB
  bf16_t* dwb  = (bf16_t*)(ws + 92577792);  //  32 MB
  float* g     = (float*)(ws + 126132224);  //  64 MB (reused as down partials)
  bf16_t* hb   = (bf16_t*)(ws + 193241088); //  32 MB  -> total ~216 MB
  float* part  = g;  // alias: g is dead once up_gemm finishes (stream-ordered)

  float debiaser = (float)(1.0 / (1e-7 + (1.0 - pow(0.99, 1000.0))));

  prep_mu_thr<<<256, 256, 0, stream>>>(med, aad, gth, debiaser, mu, thr);
  prep_x<<<4096, 256, 0, stream>>>(x, mu, xd, xb);
  transpose_cast<<<dim3(256, 64), 256, 0, stream>>>(gw, gwT);
  transpose_cast<<<dim3(256, 64), 256, 0, stream>>>(uw, upT);
  cast_bf16<<<8192, 256, 0, stream>>>(dw, dwb);
  c_init<<<32, 256, 0, stream>>>(gb, cj);
  c_part<<<256, 256, 0, stream>>>(gw, mu, cj);
  count_active<<<2048, 256, 0, stream>>>(xd, thr, dense, active);
  gate_gemm<<<dim3(64, 16), 256, 0, stream>>>(xd, thr, gwT, cj, g);
  up_gemm<<<dim3(64, 16), 256, 0, stream>>>(xb, upT, ub, g, hb);
  down_gemm<<<dim3(16, 16, 4), 256, 0, stream>>>(hb, dwb, part);
  down_reduce<<<4096, 256, 0, stream>>>(part, db, y);
}